// Round 8
// baseline (172.373 us; speedup 1.0000x reference)
//
#include <hip/hip_runtime.h>
#include <cstdint>

#define BN_EPS 1e-5f

static constexpr int NB = 8192;
static constexpr int JLIN = 500;

typedef int v4i  __attribute__((ext_vector_type(4)));
typedef int v16i __attribute__((ext_vector_type(16)));

// ---------------------------------------------------------------------------
// ws layout (h2b/h3w legacy, unused)
//  wbfrag [16][128][64] uint4  @ 4194304   2 MB
//  cdat   [640] u32            @ 6815744
//  lut    [512] u32            @ 6818304
//  wout   [160] u32            @ 6820352
//  Tlin   [512] i32            @ 6820992
//  wcfrag [9][2][64] uint4     @ 6855808
// ---------------------------------------------------------------------------

// ---------------------------------------------------------------------------
// pack kernel, grid = 525 blocks (unchanged)
// ---------------------------------------------------------------------------
__global__ __launch_bounds__(256) void pack_kernel(
    const float* __restrict__ conv1_w, const float* __restrict__ conv1_b,
    const float* __restrict__ conv2_w, const float* __restrict__ conv2_b,
    const float* __restrict__ lin_w, const float* __restrict__ lin_b,
    const float* __restrict__ out_w,
    const float* __restrict__ bn1_g, const float* __restrict__ bn1_b,
    const float* __restrict__ bn1_m, const float* __restrict__ bn1_v,
    const float* __restrict__ bn2_g, const float* __restrict__ bn2_b,
    const float* __restrict__ bn2_m, const float* __restrict__ bn2_v,
    uint4* __restrict__ wbfrag, uint32_t* __restrict__ cdat,
    uint32_t* __restrict__ lut, uint32_t* __restrict__ wout,
    int* __restrict__ Tlin, uint4* __restrict__ wcfrag)
{
    __shared__ float    s_c1w[288];
    __shared__ uint32_t s_wp[32];
    __shared__ float    s_inv1[32], s_sh1[32], s_b1[32];

    int tid = threadIdx.x;
    int b   = blockIdx.x;

    if (b < 512) {
        int e  = b * 256 + tid;
        int L  = e & 63;
        int kq = (e >> 6) & 127;
        int jt = e >> 13;
        int j  = jt * 32 + (L & 31);
        int h  = L >> 5;
        uint32_t dd[4] = {0u, 0u, 0u, 0u};
        if (j < JLIN) {
            int c  = kq >> 1, hi = kq & 1;
            int nb = (hi ? 28 : 32) - 16 * h;
            const float4* s4 = (const float4*)(lin_w + (size_t)j * 3840 +
                                               c * 60 + hi * 32 + 16 * h);
            float4 q0 = s4[0], q1 = s4[1], q2 = s4[2], q3 = s4[3];
            float qf[16] = {q0.x, q0.y, q0.z, q0.w, q1.x, q1.y, q1.z, q1.w,
                            q2.x, q2.y, q2.z, q2.w, q3.x, q3.y, q3.z, q3.w};
            #pragma unroll
            for (int i = 0; i < 16; ++i) {
                uint32_t byte = (i < nb) ? ((qf[i] > 0.0f) ? 0x01u : 0xFFu) : 0u;
                dd[i >> 2] |= byte << (8 * (i & 3));
            }
        }
        wbfrag[e] = make_uint4(dd[0], dd[1], dd[2], dd[3]);
        return;
    }

    if (b >= 520) {
        int e = (b - 520) * 256 + tid;      // 0..1279, use <1152
        if (e < 1152) {
            int t = e >> 7;
            int n = (e >> 6) & 1;
            int L = e & 63;
            int c = n * 32 + (L & 31);
            int hb = L >> 5;
            bool flip = (bn2_g[c] < 0.0f);
            uint32_t dd[4] = {0u, 0u, 0u, 0u};
            #pragma unroll
            for (int i = 0; i < 16; ++i) {
                int ic = 16 * hb + i;
                float w = conv2_w[c * 288 + ic * 9 + t];
                uint32_t byte = ((w > 0.0f) == flip) ? 0xFFu : 0x01u;
                dd[i >> 2] |= byte << (8 * (i & 3));
            }
            wcfrag[e] = make_uint4(dd[0], dd[1], dd[2], dd[3]);
        }
        return;
    }

    int mb = b - 512;
    if (mb < 2) {
        for (int i = tid; i < 288; i += 256) s_c1w[i] = conv1_w[i];
        __syncthreads();
        if (tid < 32) {
            uint32_t wp = 0;
            for (int t = 0; t < 9; ++t)
                wp |= (s_c1w[tid * 9 + t] < 0.0f ? 1u : 0u) << t;
            s_wp[tid] = wp;
            float inv = bn1_g[tid] / sqrtf(bn1_v[tid] + BN_EPS);
            s_inv1[tid] = inv;
            s_sh1[tid]  = bn1_b[tid] - bn1_m[tid] * inv;
            s_b1[tid]   = conv1_b[tid];
        }
        __syncthreads();
        uint32_t px = (uint32_t)(mb * 256 + tid);
        uint32_t word = 0;
        for (int c = 0; c < 32; ++c) {
            int d = 9 - 2 * __popc(px ^ s_wp[c]);
            float z = __fadd_rn((float)d, s_b1[c]);
            z = __fadd_rn(__fmul_rn(z, s_inv1[c]), s_sh1[c]);
            word |= (z > 0.0f ? 1u : 0u) << c;
        }
        lut[px] = word;
        return;
    }

    int idx = (mb - 2) * 256 + tid;     // 0..1535
    if (idx < 576) {
        int c = idx / 9, tap = idx % 9;
        uint32_t w = 0;
        for (int ic = 0; ic < 32; ++ic)
            w |= (conv2_w[c * 288 + ic * 9 + tap] > 0.0f ? 1u : 0u) << ic;
        float inv = bn2_g[c] / sqrtf(bn2_v[c] + BN_EPS);
        if (inv < 0.0f) w = ~w;
        cdat[tap * 64 + c] = w;
    } else if (idx < 576 + 64) {
        int c = idx - 576;
        float inv = bn2_g[c] / sqrtf(bn2_v[c] + BN_EPS);
        float sh  = bn2_b[c] - bn2_m[c] * inv;
        float b2  = conv2_b[c];
        int T = 10000;
        for (int u = -300; u <= 300; ++u) {
            float v = (inv < 0.0f) ? (float)(-u) : (float)u;
            float z = __fadd_rn(__fmul_rn(__fadd_rn(v, b2), inv), sh);
            if (z > 0.0f) { T = u; break; }
        }
        cdat[576 + c] = (uint32_t)T;
    } else if (idx < 576 + 64 + 512) {
        int j = idx - (576 + 64);
        int T = 10000;
        if (j < JLIN) {
            float lb = lin_b[j];
            int base = (int)floorf(-lb) - 2;
            for (int u = base; u <= base + 5; ++u)
                if (__fadd_rn((float)u, lb) > 0.0f) { T = u; break; }
        }
        Tlin[j] = T;
    } else if (idx < 576 + 64 + 512 + 160) {
        int t = idx - (576 + 64 + 512);
        int j = t >> 4, k = t & 15;
        uint32_t w = 0;
        for (int bb = 0; bb < 32; ++bb) {
            int jj = k * 32 + bb;
            if (jj < JLIN) w |= (out_w[j * 500 + jj] > 0.0f ? 1u : 0u) << bb;
        }
        wout[t] = w;
    }
}

// ---------------------------------------------------------------------------
// fused kernel v2: 1024 threads (16 waves), 32 samples/block, grid 256.
//  R8 changes vs R7:
//   - 16 waves -> 4 waves/SIMD (2x TLP; was 2/SIMD at 20% occupancy).
//   - conv phase: 2 samples/wave; BOTH samples' x loaded up front (sample
//     2's HBM latency hides under sample 1's conv chain; sched_barrier(0)
//     otherwise pins loads).
//   - conv MFMA rt-outer: 2 live accumulators (32 regs, was 64) to fit the
//     <=128-reg budget 1024-thread blocks require.
//   - lin2 phase: 1 jt/wave (16 waves = 16 jt), 1 accumulator.
// ---------------------------------------------------------------------------
__global__ __launch_bounds__(1024) void fused_kernel(
    const float* __restrict__ x,
    const uint32_t* __restrict__ cdat,
    const uint32_t* __restrict__ lut,
    const uint4* __restrict__ wcfrag,
    const uint4* __restrict__ wbfrag,
    const int* __restrict__ Tlin,
    const uint32_t* __restrict__ wout,
    const float* __restrict__ out_b,
    float* __restrict__ out)
{
    __shared__ uint32_t s_lut[512];
    __shared__ uint32_t s_wout[160];
    __shared__ __align__(8) uint32_t s_flat[16][44];
    __shared__ uint32_t s_words[16][288];
    __shared__ __align__(8) uint32_t h2w[32][130];
    __shared__ __align__(16) uint8_t As[32 * 520];
    __shared__ uint32_t s_h3[32][16];

    int tid  = threadIdx.x;
    int lane = tid & 63;
    int wv   = tid >> 6;                 // 0..15
    int blk  = blockIdx.x;

    if (tid < 512) s_lut[tid] = lut[tid];
    if (tid < 160) s_wout[tid] = wout[tid];
    __syncthreads();

    // ===================== conv phase =====================
    int row32 = lane & 31;
    int hb    = lane >> 5;
    int sh_hb = 16 * hb;
    int p1v   = 32 + row32; if (p1v > 59) p1v = 59;
    int wb0, wb1;
    { int oy = row32 / 12, ox = row32 - 12 * oy; wb0 = 52 * oy + 2 * ox; }
    { int oy = p1v / 12,   ox = p1v - 12 * oy;   wb1 = 52 * oy + 2 * ox; }
    int T0 = (int)cdat[576 + row32];
    int T1 = (int)cdat[576 + 32 + row32];

    // batch-load x for both samples of this wave (latency overlap)
    const float* xsa = x + ((size_t)blk * 32 + wv * 2) * 1296;
    const float* xsb = xsa + 1296;
    float xva[21], xvb[21];
    #pragma unroll
    for (int it = 0; it < 21; ++it) {
        int f = it * 64 + lane;
        xva[it] = (f < 1296) ? xsa[f] : 1.0f;
    }
    #pragma unroll
    for (int it = 0; it < 21; ++it) {
        int f = it * 64 + lane;
        xvb[it] = (f < 1296) ? xsb[f] : 1.0f;
    }

    #pragma unroll
    for (int i = 0; i < 2; ++i) {
        int sl = wv * 2 + i;

        // ---- ph1: sign bitmap ----
        #pragma unroll
        for (int it = 0; it < 21; ++it) {
            float v = i ? xvb[it] : xva[it];
            uint64_t mk = __ballot(v < 0.0f);
            if (lane == 0) *(uint64_t*)&s_flat[wv][2 * it] = mk;
        }
        asm volatile("s_waitcnt lgkmcnt(0)" ::: "memory");
        __builtin_amdgcn_sched_barrier(0);

        // ---- ph2: conv1 via LUT -> per-wave word table ----
        #pragma unroll
        for (int ii = 0; ii < 5; ++ii) {
            int wnd = ii * 64 + lane;
            if (wnd < 286) {
                int oy = wnd / 26, ox = wnd - 26 * oy;
                uint32_t pxb = 0;
                #pragma unroll
                for (int ky = 0; ky < 3; ++ky) {
                    int bitpos = 54 * (2 * oy + ky) + 2 * ox;
                    int d = bitpos >> 5, sh = bitpos & 31;
                    uint64_t wp = (uint64_t)s_flat[wv][d] |
                                  ((uint64_t)s_flat[wv][d + 1] << 32);
                    pxb |= (((uint32_t)(wp >> sh)) & 7u) << (3 * ky);
                }
                s_words[wv][wnd] = s_lut[pxb];
            }
        }
        asm volatile("s_waitcnt lgkmcnt(0)" ::: "memory");
        __builtin_amdgcn_sched_barrier(0);

        // ---- phM: rt-outer (2 live accumulators, 32 regs) ----
        uint32_t w_rt[2];
        #pragma unroll
        for (int rt = 0; rt < 2; ++rt) {
            const int wb = rt ? wb1 : wb0;
            v16i a0 = {};
            v16i a1 = {};
            #pragma unroll
            for (int t = 0; t < 9; ++t) {
                const int koff = (t / 3) * 26 + (t % 3);
                uint4 b0 = wcfrag[t * 128 + lane];
                uint4 b1 = wcfrag[t * 128 + 64 + lane];
                v4i bf0 = {(int)b0.x, (int)b0.y, (int)b0.z, (int)b0.w};
                v4i bf1 = {(int)b1.x, (int)b1.y, (int)b1.z, (int)b1.w};
                uint32_t w  = s_words[wv][wb + koff];
                uint32_t hw = w >> sh_hb;
                v4i af;
                af[0] = (int)((((hw      ) & 0xFu) * 0x204081u) & 0x01010101u);
                af[1] = (int)((((hw >> 4 ) & 0xFu) * 0x204081u) & 0x01010101u);
                af[2] = (int)((((hw >> 8 ) & 0xFu) * 0x204081u) & 0x01010101u);
                af[3] = (int)((((hw >> 12) & 0xFu) * 0x204081u) & 0x01010101u);
                a0 = __builtin_amdgcn_mfma_i32_32x32x32_i8(af, bf0, a0, 0, 0, 0);
                a1 = __builtin_amdgcn_mfma_i32_32x32x32_i8(af, bf1, a1, 0, 0, 0);
            }
            // epi for this rt
            uint32_t lw0 = 0, lw1 = 0;
            #pragma unroll
            for (int r = 0; r < 16; ++r) {
                const uint32_t pb = 1u << ((r & 3) + 8 * (r >> 2));
                if (a0[r] >= T0) lw0 |= pb;
                if (a1[r] >= T1) lw1 |= pb;
            }
            lw0 <<= 4 * hb;
            lw1 <<= 4 * hb;
            uint32_t send = hb ? lw0 : lw1;
            uint32_t recv = (uint32_t)__shfl_xor((int)send, 32);
            w_rt[rt] = recv | (hb ? lw1 : lw0);
        }
        *(uint2*)&h2w[sl][2 * lane] = make_uint2(w_rt[0], w_rt[1] & 0x0FFFFFFFu);
    }
    __syncthreads();

    // ===================== lin2 phase: 1 jt per wave =====================
    int jt = wv;
    int T  = Tlin[jt * 32 + row32];
    int smx = tid >> 4, wlx = tid & 15;          // valid for tid < 512

    v16i acc = {};
    for (int chunk = 0; chunk < 8; ++chunk) {
        if (tid < 512) {
            uint32_t w = h2w[smx][chunk * 16 + wlx];
            uint32_t dw[8];
            #pragma unroll
            for (int q = 0; q < 8; ++q)
                dw[q] = (((w >> (4 * q)) & 0xFu) * 0x204081u) & 0x01010101u;
            uint64_t* dst = (uint64_t*)(As + smx * 520 + wlx * 32);
            dst[0] = (uint64_t)dw[0] | ((uint64_t)dw[1] << 32);
            dst[1] = (uint64_t)dw[2] | ((uint64_t)dw[3] << 32);
            dst[2] = (uint64_t)dw[4] | ((uint64_t)dw[5] << 32);
            dst[3] = (uint64_t)dw[6] | ((uint64_t)dw[7] << 32);
        }
        __syncthreads();

        const uint4* bp = wbfrag + ((size_t)jt * 128 + chunk * 16) * 64 + lane;
        #pragma unroll 4
        for (int kq = 0; kq < 16; ++kq) {
            uint4 bw = bp[kq * 64];
            v4i bf = {(int)bw.x, (int)bw.y, (int)bw.z, (int)bw.w};
            const uint8_t* ap = As + row32 * 520 + kq * 32 + hb * 16;
            uint64_t lo0 = *(const uint64_t*)ap;
            uint64_t hi0 = *(const uint64_t*)(ap + 8);
            v4i a0 = {(int)(uint32_t)lo0, (int)(lo0 >> 32),
                      (int)(uint32_t)hi0, (int)(hi0 >> 32)};
            acc = __builtin_amdgcn_mfma_i32_32x32x32_i8(a0, bf, acc, 0, 0, 0);
        }
        __syncthreads();
    }

    #pragma unroll
    for (int r = 0; r < 16; ++r) {
        int row0 = (r & 3) + 8 * (r >> 2);
        uint64_t mk = __ballot(acc[r] >= T);
        if (lane == 0) {
            s_h3[row0][jt]     = (uint32_t)mk;
            s_h3[row0 + 4][jt] = (uint32_t)(mk >> 32);
        }
    }
    __syncthreads();

    // ===================== out phase =====================
    if (tid < 320) {
        int sl = tid / 10, o = tid - 10 * sl;
        int B = 0, P = 0;
        #pragma unroll
        for (int k = 0; k < 16; ++k) {
            uint32_t w = s_h3[sl][k];
            B += __popc(w);
            P += __popc(w & s_wout[o * 16 + k]);
        }
        out[((size_t)blk * 32 + sl) * 10 + o] = __fadd_rn((float)(2 * P - B), out_b[o]);
    }
}

// ---------------------------------------------------------------------------
extern "C" void kernel_launch(void* const* d_in, const int* in_sizes, int n_in,
                              void* d_out, int out_size, void* d_ws, size_t ws_size,
                              hipStream_t stream)
{
    const float* x       = (const float*)d_in[0];
    const float* conv1_w = (const float*)d_in[1];
    const float* conv1_b = (const float*)d_in[2];
    const float* bn1_g   = (const float*)d_in[3];
    const float* bn1_b   = (const float*)d_in[4];
    const float* bn1_m   = (const float*)d_in[5];
    const float* bn1_v   = (const float*)d_in[6];
    const float* conv2_w = (const float*)d_in[7];
    const float* conv2_b = (const float*)d_in[8];
    const float* bn2_g   = (const float*)d_in[9];
    const float* bn2_b   = (const float*)d_in[10];
    const float* bn2_m   = (const float*)d_in[11];
    const float* bn2_v   = (const float*)d_in[12];
    const float* lin_w   = (const float*)d_in[13];
    const float* lin_b   = (const float*)d_in[14];
    const float* out_w   = (const float*)d_in[15];
    const float* out_b   = (const float*)d_in[16];

    char* ws = (char*)d_ws;
    uint4*    wbfrag = (uint4*)   (ws + 4194304);
    uint32_t* cdat   = (uint32_t*)(ws + 6815744);
    uint32_t* lut    = (uint32_t*)(ws + 6818304);
    uint32_t* wout   = (uint32_t*)(ws + 6820352);
    int*      Tlin   = (int*)     (ws + 6820992);
    uint4*    wcfrag = (uint4*)   (ws + 6855808);

    pack_kernel<<<525, 256, 0, stream>>>(conv1_w, conv1_b, conv2_w, conv2_b,
                                         lin_w, lin_b, out_w,
                                         bn1_g, bn1_b, bn1_m, bn1_v,
                                         bn2_g, bn2_b, bn2_m, bn2_v,
                                         wbfrag, cdat, lut, wout, Tlin, wcfrag);
    fused_kernel<<<256, 1024, 0, stream>>>(x, cdat, lut, wcfrag, wbfrag,
                                           Tlin, wout, out_b, (float*)d_out);
}

// Round 10
// 164.872 us; speedup vs baseline: 1.0455x; 1.0455x over previous
//
#include <hip/hip_runtime.h>
#include <cstdint>

#define BN_EPS 1e-5f

static constexpr int NB = 8192;
static constexpr int JLIN = 500;

typedef int v4i  __attribute__((ext_vector_type(4)));
typedef int v16i __attribute__((ext_vector_type(16)));

// ---------------------------------------------------------------------------
// ws layout
//  wbbit  [16][64][64] u32     @ 0         256 KB (lin B sign bits, lane order;
//                                           u32 = {even kq lo16, odd kq hi16})
//  cdat   [640] u32            @ 6815744
//  lut    [512] u32            @ 6818304
//  wout   [160] u32            @ 6820352
//  Tlin   [512] i32            @ 6820992
//  wcfrag [9][2][64] uint4     @ 6855808
// ---------------------------------------------------------------------------

// ---------------------------------------------------------------------------
// pack kernel, grid = 525 blocks. R9: b<512 branch emits bit-packed B
// (2 B/thread stores instead of 16 B). Padding safety: A-side k-bits
// 60..63 per channel-pair are zero, so garbage +-1 B there contributes 0;
// j>=500 columns stay below Tlin=10000 regardless.
// ---------------------------------------------------------------------------
__global__ __launch_bounds__(256) void pack_kernel(
    const float* __restrict__ conv1_w, const float* __restrict__ conv1_b,
    const float* __restrict__ conv2_w, const float* __restrict__ conv2_b,
    const float* __restrict__ lin_w, const float* __restrict__ lin_b,
    const float* __restrict__ out_w,
    const float* __restrict__ bn1_g, const float* __restrict__ bn1_b,
    const float* __restrict__ bn1_m, const float* __restrict__ bn1_v,
    const float* __restrict__ bn2_g, const float* __restrict__ bn2_b,
    const float* __restrict__ bn2_m, const float* __restrict__ bn2_v,
    uint16_t* __restrict__ wbbith, uint32_t* __restrict__ cdat,
    uint32_t* __restrict__ lut, uint32_t* __restrict__ wout,
    int* __restrict__ Tlin, uint4* __restrict__ wcfrag)
{
    __shared__ float    s_c1w[288];
    __shared__ uint32_t s_wp[32];
    __shared__ float    s_inv1[32], s_sh1[32], s_b1[32];

    int tid = threadIdx.x;
    int b   = blockIdx.x;

    if (b < 512) {
        int e  = b * 256 + tid;
        int L  = e & 63;
        int kq = (e >> 6) & 127;
        int jt = e >> 13;
        int j  = jt * 32 + (L & 31);
        int h  = L >> 5;
        uint32_t bits = 0;
        if (j < JLIN) {
            const float4* s4 = (const float4*)(lin_w + (size_t)j * 3840 +
                                               (kq >> 1) * 60 + (kq & 1) * 32 + 16 * h);
            float4 q0 = s4[0], q1 = s4[1], q2 = s4[2], q3 = s4[3];
            float qf[16] = {q0.x, q0.y, q0.z, q0.w, q1.x, q1.y, q1.z, q1.w,
                            q2.x, q2.y, q2.z, q2.w, q3.x, q3.y, q3.z, q3.w};
            #pragma unroll
            for (int i = 0; i < 16; ++i)
                if (!(qf[i] > 0.0f)) bits |= 1u << i;   // bit=1 <=> -1
        }
        wbbith[((size_t)(jt * 64 + (kq >> 1)) * 64 + L) * 2 + (kq & 1)] =
            (uint16_t)bits;
        return;
    }

    if (b >= 520) {
        int e = (b - 520) * 256 + tid;      // 0..1279, use <1152
        if (e < 1152) {
            int t = e >> 7;
            int n = (e >> 6) & 1;
            int L = e & 63;
            int c = n * 32 + (L & 31);
            int hb = L >> 5;
            bool flip = (bn2_g[c] < 0.0f);
            uint32_t dd[4] = {0u, 0u, 0u, 0u};
            #pragma unroll
            for (int i = 0; i < 16; ++i) {
                int ic = 16 * hb + i;
                float w = conv2_w[c * 288 + ic * 9 + t];
                uint32_t byte = ((w > 0.0f) == flip) ? 0xFFu : 0x01u;
                dd[i >> 2] |= byte << (8 * (i & 3));
            }
            wcfrag[e] = make_uint4(dd[0], dd[1], dd[2], dd[3]);
        }
        return;
    }

    int mb = b - 512;
    if (mb < 2) {
        for (int i = tid; i < 288; i += 256) s_c1w[i] = conv1_w[i];
        __syncthreads();
        if (tid < 32) {
            uint32_t wp = 0;
            for (int t = 0; t < 9; ++t)
                wp |= (s_c1w[tid * 9 + t] < 0.0f ? 1u : 0u) << t;
            s_wp[tid] = wp;
            float inv = bn1_g[tid] / sqrtf(bn1_v[tid] + BN_EPS);
            s_inv1[tid] = inv;
            s_sh1[tid]  = bn1_b[tid] - bn1_m[tid] * inv;
            s_b1[tid]   = conv1_b[tid];
        }
        __syncthreads();
        uint32_t px = (uint32_t)(mb * 256 + tid);
        uint32_t word = 0;
        for (int c = 0; c < 32; ++c) {
            int d = 9 - 2 * __popc(px ^ s_wp[c]);
            float z = __fadd_rn((float)d, s_b1[c]);
            z = __fadd_rn(__fmul_rn(z, s_inv1[c]), s_sh1[c]);
            word |= (z > 0.0f ? 1u : 0u) << c;
        }
        lut[px] = word;
        return;
    }

    int idx = (mb - 2) * 256 + tid;     // 0..1535
    if (idx < 576) {
        int c = idx / 9, tap = idx % 9;
        uint32_t w = 0;
        for (int ic = 0; ic < 32; ++ic)
            w |= (conv2_w[c * 288 + ic * 9 + tap] > 0.0f ? 1u : 0u) << ic;
        float inv = bn2_g[c] / sqrtf(bn2_v[c] + BN_EPS);
        if (inv < 0.0f) w = ~w;
        cdat[tap * 64 + c] = w;
    } else if (idx < 576 + 64) {
        int c = idx - 576;
        float inv = bn2_g[c] / sqrtf(bn2_v[c] + BN_EPS);
        float sh  = bn2_b[c] - bn2_m[c] * inv;
        float b2  = conv2_b[c];
        int T = 10000;
        for (int u = -300; u <= 300; ++u) {
            float v = (inv < 0.0f) ? (float)(-u) : (float)u;
            float z = __fadd_rn(__fmul_rn(__fadd_rn(v, b2), inv), sh);
            if (z > 0.0f) { T = u; break; }
        }
        cdat[576 + c] = (uint32_t)T;
    } else if (idx < 576 + 64 + 512) {
        int j = idx - (576 + 64);
        int T = 10000;
        if (j < JLIN) {
            float lb = lin_b[j];
            int base = (int)floorf(-lb) - 2;
            for (int u = base; u <= base + 5; ++u)
                if (__fadd_rn((float)u, lb) > 0.0f) { T = u; break; }
        }
        Tlin[j] = T;
    } else if (idx < 576 + 64 + 512 + 160) {
        int t = idx - (576 + 64 + 512);
        int j = t >> 4, k = t & 15;
        uint32_t w = 0;
        for (int bb = 0; bb < 32; ++bb) {
            int jj = k * 32 + bb;
            if (jj < JLIN) w |= (out_w[j * 500 + jj] > 0.0f ? 1u : 0u) << bb;
        }
        wout[t] = w;
    }
}

// ---------------------------------------------------------------------------
// fused kernel v3: 512 threads (8 waves), 32 samples/block, grid 256.
//  R9 changes vs R7:
//   - conv phase: next-sample x prefetched into registers (vmcnt loads stay
//     in flight across the lgkm drains; hides HBM latency under conv chain).
//   - lin2 phase: BARRIER-FREE. A expanded in-register from h2w words
//     (ds_read_b64/kqp); B from bit-packed wbbit (256 KB total, 16x less
//     traffic than wbfrag bytes) via b01*0xFE+0x01010101 -> +-1 bytes.
//     As staging LDS + 16 __syncthreads deleted.
// ---------------------------------------------------------------------------
__global__ __launch_bounds__(512) void fused_kernel(
    const float* __restrict__ x,
    const uint32_t* __restrict__ cdat,
    const uint32_t* __restrict__ lut,
    const uint4* __restrict__ wcfrag,
    const uint32_t* __restrict__ wbbit,
    const int* __restrict__ Tlin,
    const uint32_t* __restrict__ wout,
    const float* __restrict__ out_b,
    float* __restrict__ out)
{
    __shared__ uint32_t s_lut[512];
    __shared__ uint32_t s_wout[160];
    __shared__ __align__(8) uint32_t s_flat[8][44];
    __shared__ uint32_t s_words[8][288];
    __shared__ __align__(8) uint32_t h2w[32][130];
    __shared__ uint32_t s_h3[32][16];

    int tid  = threadIdx.x;
    int lane = tid & 63;
    int wv   = tid >> 6;                 // 0..7
    int blk  = blockIdx.x;

    s_lut[tid] = lut[tid];
    if (tid < 160) s_wout[tid] = wout[tid];
    __syncthreads();

    // ===================== conv phase =====================
    int row32 = lane & 63 & 31;
    int hb    = lane >> 5;
    int sh_hb = 16 * hb;
    int p1v   = 32 + row32; if (p1v > 59) p1v = 59;
    int wb0, wb1;
    { int oy = row32 / 12, ox = row32 - 12 * oy; wb0 = 52 * oy + 2 * ox; }
    { int oy = p1v / 12,   ox = p1v - 12 * oy;   wb1 = 52 * oy + 2 * ox; }
    int T0 = (int)cdat[576 + row32];
    int T1 = (int)cdat[576 + 32 + row32];

    const float* xs0 = x + ((size_t)blk * 32 + wv * 4) * 1296;
    float xv[21];
    #pragma unroll
    for (int it = 0; it < 21; ++it) {
        int f = it * 64 + lane;
        xv[it] = (f < 1296) ? xs0[f] : 1.0f;
    }

    #pragma unroll
    for (int i = 0; i < 4; ++i) {
        int sl = wv * 4 + i;

        // prefetch next sample's x (latency hides under this sample's chain)
        float xvn[21];
        if (i < 3) {
            const float* xn = xs0 + (size_t)(i + 1) * 1296;
            #pragma unroll
            for (int it = 0; it < 21; ++it) {
                int f = it * 64 + lane;
                xvn[it] = (f < 1296) ? xn[f] : 1.0f;
            }
        }

        // ---- ph1: sign bitmap ----
        #pragma unroll
        for (int it = 0; it < 21; ++it) {
            uint64_t mk = __ballot(xv[it] < 0.0f);
            if (lane == 0) *(uint64_t*)&s_flat[wv][2 * it] = mk;
        }
        asm volatile("s_waitcnt lgkmcnt(0)" ::: "memory");
        __builtin_amdgcn_sched_barrier(0);

        // ---- ph2: conv1 via LUT -> per-wave word table ----
        #pragma unroll
        for (int ii = 0; ii < 5; ++ii) {
            int wnd = ii * 64 + lane;
            if (wnd < 286) {
                int oy = wnd / 26, ox = wnd - 26 * oy;
                uint32_t pxb = 0;
                #pragma unroll
                for (int ky = 0; ky < 3; ++ky) {
                    int bitpos = 54 * (2 * oy + ky) + 2 * ox;
                    int d = bitpos >> 5, sh = bitpos & 31;
                    uint64_t wp = (uint64_t)s_flat[wv][d] |
                                  ((uint64_t)s_flat[wv][d + 1] << 32);
                    pxb |= (((uint32_t)(wp >> sh)) & 7u) << (3 * ky);
                }
                s_words[wv][wnd] = s_lut[pxb];
            }
        }
        asm volatile("s_waitcnt lgkmcnt(0)" ::: "memory");
        __builtin_amdgcn_sched_barrier(0);

        // ---- phM (R7 4-acc t-loop) ----
        v16i acc[2][2] = {};
        #pragma unroll
        for (int t = 0; t < 9; ++t) {
            const int koff = (t / 3) * 26 + (t % 3);
            uint4 b0 = wcfrag[t * 128 + lane];
            uint4 b1 = wcfrag[t * 128 + 64 + lane];
            v4i bf0 = {(int)b0.x, (int)b0.y, (int)b0.z, (int)b0.w};
            v4i bf1 = {(int)b1.x, (int)b1.y, (int)b1.z, (int)b1.w};
            #pragma unroll
            for (int rt = 0; rt < 2; ++rt) {
                uint32_t w  = s_words[wv][(rt ? wb1 : wb0) + koff];
                uint32_t hw = w >> sh_hb;
                v4i af;
                af[0] = (int)((((hw      ) & 0xFu) * 0x204081u) & 0x01010101u);
                af[1] = (int)((((hw >> 4 ) & 0xFu) * 0x204081u) & 0x01010101u);
                af[2] = (int)((((hw >> 8 ) & 0xFu) * 0x204081u) & 0x01010101u);
                af[3] = (int)((((hw >> 12) & 0xFu) * 0x204081u) & 0x01010101u);
                acc[rt][0] = __builtin_amdgcn_mfma_i32_32x32x32_i8(af, bf0, acc[rt][0], 0, 0, 0);
                acc[rt][1] = __builtin_amdgcn_mfma_i32_32x32x32_i8(af, bf1, acc[rt][1], 0, 0, 0);
            }
        }

        // ---- epi: in-register word assembly ----
        {
            uint32_t w_rt[2];
            #pragma unroll
            for (int rt = 0; rt < 2; ++rt) {
                uint32_t lw0 = 0, lw1 = 0;
                #pragma unroll
                for (int r = 0; r < 16; ++r) {
                    const uint32_t pb = 1u << ((r & 3) + 8 * (r >> 2));
                    if (acc[rt][0][r] >= T0) lw0 |= pb;
                    if (acc[rt][1][r] >= T1) lw1 |= pb;
                }
                lw0 <<= 4 * hb;
                lw1 <<= 4 * hb;
                uint32_t send = hb ? lw0 : lw1;
                uint32_t recv = (uint32_t)__shfl_xor((int)send, 32);
                w_rt[rt] = recv | (hb ? lw1 : lw0);
            }
            *(uint2*)&h2w[sl][2 * lane] = make_uint2(w_rt[0], w_rt[1] & 0x0FFFFFFFu);
        }

        if (i < 3) {
            #pragma unroll
            for (int it = 0; it < 21; ++it) xv[it] = xvn[it];
        }
    }
    __syncthreads();

    // ========== lin2 phase: barrier-free, 2 jt/wave ==========
    int jt0 = wv, jt1 = wv + 8;
    int Ta = Tlin[jt0 * 32 + row32];
    int Tb = Tlin[jt1 * 32 + row32];
    const uint32_t* bb0 = wbbit + (size_t)jt0 * 64 * 64 + lane;
    const uint32_t* bb1 = wbbit + (size_t)jt1 * 64 * 64 + lane;

    v16i acc0 = {};
    v16i acc1 = {};
    #pragma unroll 4
    for (int kqp = 0; kqp < 64; ++kqp) {
        uint32_t bw0 = bb0[kqp * 64];
        uint32_t bw1 = bb1[kqp * 64];
        uint2 awp = *(const uint2*)&h2w[row32][2 * kqp];
        #pragma unroll
        for (int hf = 0; hf < 2; ++hf) {
            uint32_t aw = hf ? awp.y : awp.x;
            uint32_t hw = aw >> sh_hb;
            v4i af;
            af[0] = (int)((((hw      ) & 0xFu) * 0x204081u) & 0x01010101u);
            af[1] = (int)((((hw >> 4 ) & 0xFu) * 0x204081u) & 0x01010101u);
            af[2] = (int)((((hw >> 8 ) & 0xFu) * 0x204081u) & 0x01010101u);
            af[3] = (int)((((hw >> 12) & 0xFu) * 0x204081u) & 0x01010101u);
            uint32_t s0 = hf ? (bw0 >> 16) : (bw0 & 0xFFFFu);
            uint32_t s1 = hf ? (bw1 >> 16) : (bw1 & 0xFFFFu);
            v4i bf0, bf1;
            #pragma unroll
            for (int q = 0; q < 4; ++q) {
                uint32_t b01 = (((s0 >> (4 * q)) & 0xFu) * 0x204081u) & 0x01010101u;
                bf0[q] = (int)(b01 * 0xFEu + 0x01010101u);
                uint32_t c01 = (((s1 >> (4 * q)) & 0xFu) * 0x204081u) & 0x01010101u;
                bf1[q] = (int)(c01 * 0xFEu + 0x01010101u);
            }
            acc0 = __builtin_amdgcn_mfma_i32_32x32x32_i8(af, bf0, acc0, 0, 0, 0);
            acc1 = __builtin_amdgcn_mfma_i32_32x32x32_i8(af, bf1, acc1, 0, 0, 0);
        }
    }

    #pragma unroll
    for (int r = 0; r < 16; ++r) {
        int row0 = (r & 3) + 8 * (r >> 2);
        uint64_t mk0 = __ballot(acc0[r] >= Ta);
        uint64_t mk1 = __ballot(acc1[r] >= Tb);
        if (lane == 0) {
            s_h3[row0][jt0]     = (uint32_t)mk0;
            s_h3[row0 + 4][jt0] = (uint32_t)(mk0 >> 32);
            s_h3[row0][jt1]     = (uint32_t)mk1;
            s_h3[row0 + 4][jt1] = (uint32_t)(mk1 >> 32);
        }
    }
    __syncthreads();

    // ===================== out phase =====================
    if (tid < 320) {
        int sl = tid / 10, o = tid - 10 * sl;
        int B = 0, P = 0;
        #pragma unroll
        for (int k = 0; k < 16; ++k) {
            uint32_t w = s_h3[sl][k];
            B += __popc(w);
            P += __popc(w & s_wout[o * 16 + k]);
        }
        out[((size_t)blk * 32 + sl) * 10 + o] = __fadd_rn((float)(2 * P - B), out_b[o]);
    }
}

// ---------------------------------------------------------------------------
extern "C" void kernel_launch(void* const* d_in, const int* in_sizes, int n_in,
                              void* d_out, int out_size, void* d_ws, size_t ws_size,
                              hipStream_t stream)
{
    const float* x       = (const float*)d_in[0];
    const float* conv1_w = (const float*)d_in[1];
    const float* conv1_b = (const float*)d_in[2];
    const float* bn1_g   = (const float*)d_in[3];
    const float* bn1_b   = (const float*)d_in[4];
    const float* bn1_m   = (const float*)d_in[5];
    const float* bn1_v   = (const float*)d_in[6];
    const float* conv2_w = (const float*)d_in[7];
    const float* conv2_b = (const float*)d_in[8];
    const float* bn2_g   = (const float*)d_in[9];
    const float* bn2_b   = (const float*)d_in[10];
    const float* bn2_m   = (const float*)d_in[11];
    const float* bn2_v   = (const float*)d_in[12];
    const float* lin_w   = (const float*)d_in[13];
    const float* lin_b   = (const float*)d_in[14];
    const float* out_w   = (const float*)d_in[15];
    const float* out_b   = (const float*)d_in[16];

    char* ws = (char*)d_ws;
    uint32_t* wbbit  = (uint32_t*)(ws + 0);
    uint32_t* cdat   = (uint32_t*)(ws + 6815744);
    uint32_t* lut    = (uint32_t*)(ws + 6818304);
    uint32_t* wout   = (uint32_t*)(ws + 6820352);
    int*      Tlin   = (int*)     (ws + 6820992);
    uint4*    wcfrag = (uint4*)   (ws + 6855808);

    pack_kernel<<<525, 256, 0, stream>>>(conv1_w, conv1_b, conv2_w, conv2_b,
                                         lin_w, lin_b, out_w,
                                         bn1_g, bn1_b, bn1_m, bn1_v,
                                         bn2_g, bn2_b, bn2_m, bn2_v,
                                         (uint16_t*)wbbit, cdat, lut, wout,
                                         Tlin, wcfrag);
    fused_kernel<<<256, 512, 0, stream>>>(x, cdat, lut, wcfrag, wbbit,
                                          Tlin, wout, out_b, (float*)d_out);
}

// Round 11
// 163.250 us; speedup vs baseline: 1.0559x; 1.0099x over previous
//
#include <hip/hip_runtime.h>
#include <cstdint>

#define BN_EPS 1e-5f

static constexpr int NB = 8192;
static constexpr int JLIN = 500;

typedef int v4i  __attribute__((ext_vector_type(4)));
typedef int v16i __attribute__((ext_vector_type(16)));

// ---------------------------------------------------------------------------
// ws layout
//  h2b    [8192][128] u32      @ 0         4 MB
//  wbfrag [16][128][64] uint4  @ 4194304   2 MB
//  h3w    [8192][16] u32       @ 6291456   512 KB
//  cdat   [640] u32            @ 6815744
//  lut    [512] u32            @ 6818304
//  wout   [160] u32            @ 6820352
//  Tlin   [512] i32            @ 6820992
//  wcfrag [9][2][64] uint4     @ 6855808
// ---------------------------------------------------------------------------

// ---------------------------------------------------------------------------
// pack kernel, grid = 525 blocks (R5 float4 lin-B loads)
// ---------------------------------------------------------------------------
__global__ __launch_bounds__(256) void pack_kernel(
    const float* __restrict__ conv1_w, const float* __restrict__ conv1_b,
    const float* __restrict__ conv2_w, const float* __restrict__ conv2_b,
    const float* __restrict__ lin_w, const float* __restrict__ lin_b,
    const float* __restrict__ out_w,
    const float* __restrict__ bn1_g, const float* __restrict__ bn1_b,
    const float* __restrict__ bn1_m, const float* __restrict__ bn1_v,
    const float* __restrict__ bn2_g, const float* __restrict__ bn2_b,
    const float* __restrict__ bn2_m, const float* __restrict__ bn2_v,
    uint4* __restrict__ wbfrag, uint32_t* __restrict__ cdat,
    uint32_t* __restrict__ lut, uint32_t* __restrict__ wout,
    int* __restrict__ Tlin, uint4* __restrict__ wcfrag)
{
    __shared__ float    s_c1w[288];
    __shared__ uint32_t s_wp[32];
    __shared__ float    s_inv1[32], s_sh1[32], s_b1[32];

    int tid = threadIdx.x;
    int b   = blockIdx.x;

    if (b < 512) {
        int e  = b * 256 + tid;
        int L  = e & 63;
        int kq = (e >> 6) & 127;
        int jt = e >> 13;
        int j  = jt * 32 + (L & 31);
        int h  = L >> 5;
        uint32_t dd[4] = {0u, 0u, 0u, 0u};
        if (j < JLIN) {
            int c  = kq >> 1, hi = kq & 1;
            int nb = (hi ? 28 : 32) - 16 * h;
            const float4* s4 = (const float4*)(lin_w + (size_t)j * 3840 +
                                               c * 60 + hi * 32 + 16 * h);
            float4 q0 = s4[0], q1 = s4[1], q2 = s4[2], q3 = s4[3];
            float qf[16] = {q0.x, q0.y, q0.z, q0.w, q1.x, q1.y, q1.z, q1.w,
                            q2.x, q2.y, q2.z, q2.w, q3.x, q3.y, q3.z, q3.w};
            #pragma unroll
            for (int i = 0; i < 16; ++i) {
                uint32_t byte = (i < nb) ? ((qf[i] > 0.0f) ? 0x01u : 0xFFu) : 0u;
                dd[i >> 2] |= byte << (8 * (i & 3));
            }
        }
        wbfrag[e] = make_uint4(dd[0], dd[1], dd[2], dd[3]);
        return;
    }

    if (b >= 520) {
        int e = (b - 520) * 256 + tid;      // 0..1279, use <1152
        if (e < 1152) {
            int t = e >> 7;
            int n = (e >> 6) & 1;
            int L = e & 63;
            int c = n * 32 + (L & 31);
            int hb = L >> 5;
            bool flip = (bn2_g[c] < 0.0f);
            uint32_t dd[4] = {0u, 0u, 0u, 0u};
            #pragma unroll
            for (int i = 0; i < 16; ++i) {
                int ic = 16 * hb + i;
                float w = conv2_w[c * 288 + ic * 9 + t];
                uint32_t byte = ((w > 0.0f) == flip) ? 0xFFu : 0x01u;
                dd[i >> 2] |= byte << (8 * (i & 3));
            }
            wcfrag[e] = make_uint4(dd[0], dd[1], dd[2], dd[3]);
        }
        return;
    }

    int mb = b - 512;
    if (mb < 2) {
        for (int i = tid; i < 288; i += 256) s_c1w[i] = conv1_w[i];
        __syncthreads();
        if (tid < 32) {
            uint32_t wp = 0;
            for (int t = 0; t < 9; ++t)
                wp |= (s_c1w[tid * 9 + t] < 0.0f ? 1u : 0u) << t;
            s_wp[tid] = wp;
            float inv = bn1_g[tid] / sqrtf(bn1_v[tid] + BN_EPS);
            s_inv1[tid] = inv;
            s_sh1[tid]  = bn1_b[tid] - bn1_m[tid] * inv;
            s_b1[tid]   = conv1_b[tid];
        }
        __syncthreads();
        uint32_t px = (uint32_t)(mb * 256 + tid);
        uint32_t word = 0;
        for (int c = 0; c < 32; ++c) {
            int d = 9 - 2 * __popc(px ^ s_wp[c]);
            float z = __fadd_rn((float)d, s_b1[c]);
            z = __fadd_rn(__fmul_rn(z, s_inv1[c]), s_sh1[c]);
            word |= (z > 0.0f ? 1u : 0u) << c;
        }
        lut[px] = word;
        return;
    }

    int idx = (mb - 2) * 256 + tid;     // 0..1535
    if (idx < 576) {
        int c = idx / 9, tap = idx % 9;
        uint32_t w = 0;
        for (int ic = 0; ic < 32; ++ic)
            w |= (conv2_w[c * 288 + ic * 9 + tap] > 0.0f ? 1u : 0u) << ic;
        float inv = bn2_g[c] / sqrtf(bn2_v[c] + BN_EPS);
        if (inv < 0.0f) w = ~w;
        cdat[tap * 64 + c] = w;
    } else if (idx < 576 + 64) {
        int c = idx - 576;
        float inv = bn2_g[c] / sqrtf(bn2_v[c] + BN_EPS);
        float sh  = bn2_b[c] - bn2_m[c] * inv;
        float b2  = conv2_b[c];
        int T = 10000;
        for (int u = -300; u <= 300; ++u) {
            float v = (inv < 0.0f) ? (float)(-u) : (float)u;
            float z = __fadd_rn(__fmul_rn(__fadd_rn(v, b2), inv), sh);
            if (z > 0.0f) { T = u; break; }
        }
        cdat[576 + c] = (uint32_t)T;
    } else if (idx < 576 + 64 + 512) {
        int j = idx - (576 + 64);
        int T = 10000;
        if (j < JLIN) {
            float lb = lin_b[j];
            int base = (int)floorf(-lb) - 2;
            for (int u = base; u <= base + 5; ++u)
                if (__fadd_rn((float)u, lb) > 0.0f) { T = u; break; }
        }
        Tlin[j] = T;
    } else if (idx < 576 + 64 + 512 + 160) {
        int t = idx - (576 + 64 + 512);
        int j = t >> 4, k = t & 15;
        uint32_t w = 0;
        for (int bb = 0; bb < 32; ++bb) {
            int jj = k * 32 + bb;
            if (jj < JLIN) w |= (out_w[j * 500 + jj] > 0.0f ? 1u : 0u) << bb;
        }
        wout[t] = w;
    }
}

// ---------------------------------------------------------------------------
// conv kernel (R4, best measured): ONE WAVE = ONE SAMPLE, in-register epi.
// 4 samples/block, 2048 blocks.
// ---------------------------------------------------------------------------
__global__ __launch_bounds__(256) void conv_kernel(
    const float* __restrict__ x,
    const uint32_t* __restrict__ cdat,
    const uint32_t* __restrict__ lut,
    const uint4* __restrict__ wcfrag,
    uint32_t* __restrict__ h2b)
{
    __shared__ uint32_t s_lut[512];
    __shared__ __align__(8) uint32_t s_flat[4][44];
    __shared__ uint32_t s_words[4][288];

    int tid  = threadIdx.x;
    int lane = tid & 63;
    int wv   = tid >> 6;
    int s    = blockIdx.x * 4 + wv;

    s_lut[tid]       = lut[tid];
    s_lut[tid + 256] = lut[tid + 256];
    __syncthreads();

    // ---- ph1: sign bitmap ----
    const float* xs = x + (size_t)s * 1296;
    float xv[21];
    #pragma unroll
    for (int it = 0; it < 21; ++it) {
        int f = it * 64 + lane;
        xv[it] = (f < 1296) ? xs[f] : 1.0f;
    }
    #pragma unroll
    for (int it = 0; it < 21; ++it) {
        uint64_t mk = __ballot(xv[it] < 0.0f);
        if (lane == 0) *(uint64_t*)&s_flat[wv][2 * it] = mk;
    }
    asm volatile("s_waitcnt lgkmcnt(0)" ::: "memory");
    __builtin_amdgcn_sched_barrier(0);

    // ---- ph2: conv1 via LUT -> per-wave word table ----
    #pragma unroll
    for (int ii = 0; ii < 5; ++ii) {
        int wnd = ii * 64 + lane;
        if (wnd < 286) {
            int oy = wnd / 26, ox = wnd - 26 * oy;
            uint32_t pxb = 0;
            #pragma unroll
            for (int ky = 0; ky < 3; ++ky) {
                int bitpos = 54 * (2 * oy + ky) + 2 * ox;
                int d = bitpos >> 5, sh = bitpos & 31;
                uint64_t wp = (uint64_t)s_flat[wv][d] |
                              ((uint64_t)s_flat[wv][d + 1] << 32);
                pxb |= (((uint32_t)(wp >> sh)) & 7u) << (3 * ky);
            }
            s_words[wv][wnd] = s_lut[pxb];
        }
    }
    asm volatile("s_waitcnt lgkmcnt(0)" ::: "memory");
    __builtin_amdgcn_sched_barrier(0);

    // ---- phM: 2 row-tiles x 2 ch-tiles, 9 accumulating taps ----
    int row32 = lane & 31;
    int hb    = lane >> 5;
    int sh_hb = 16 * hb;
    int p1v   = 32 + row32; if (p1v > 59) p1v = 59;
    int wb0, wb1;
    { int oy = row32 / 12, ox = row32 - 12 * oy; wb0 = 52 * oy + 2 * ox; }
    { int oy = p1v / 12,   ox = p1v - 12 * oy;   wb1 = 52 * oy + 2 * ox; }

    v16i acc[2][2] = {};
    #pragma unroll
    for (int t = 0; t < 9; ++t) {
        const int koff = (t / 3) * 26 + (t % 3);
        uint4 b0 = wcfrag[t * 128 + lane];
        uint4 b1 = wcfrag[t * 128 + 64 + lane];
        v4i bf0 = {(int)b0.x, (int)b0.y, (int)b0.z, (int)b0.w};
        v4i bf1 = {(int)b1.x, (int)b1.y, (int)b1.z, (int)b1.w};
        #pragma unroll
        for (int rt = 0; rt < 2; ++rt) {
            uint32_t w  = s_words[wv][(rt ? wb1 : wb0) + koff];
            uint32_t hw = w >> sh_hb;
            v4i af;
            af[0] = (int)((((hw      ) & 0xFu) * 0x204081u) & 0x01010101u);
            af[1] = (int)((((hw >> 4 ) & 0xFu) * 0x204081u) & 0x01010101u);
            af[2] = (int)((((hw >> 8 ) & 0xFu) * 0x204081u) & 0x01010101u);
            af[3] = (int)((((hw >> 12) & 0xFu) * 0x204081u) & 0x01010101u);
            acc[rt][0] = __builtin_amdgcn_mfma_i32_32x32x32_i8(af, bf0, acc[rt][0], 0, 0, 0);
            acc[rt][1] = __builtin_amdgcn_mfma_i32_32x32x32_i8(af, bf1, acc[rt][1], 0, 0, 0);
        }
    }

    // ---- epi: in-register word assembly ----
    {
        int T0 = (int)cdat[576 + row32];
        int T1 = (int)cdat[576 + 32 + row32];
        uint32_t w_rt[2];
        #pragma unroll
        for (int rt = 0; rt < 2; ++rt) {
            uint32_t lw0 = 0, lw1 = 0;
            #pragma unroll
            for (int r = 0; r < 16; ++r) {
                const uint32_t pb = 1u << ((r & 3) + 8 * (r >> 2));
                if (acc[rt][0][r] >= T0) lw0 |= pb;
                if (acc[rt][1][r] >= T1) lw1 |= pb;
            }
            lw0 <<= 4 * hb;
            lw1 <<= 4 * hb;
            uint32_t send = hb ? lw0 : lw1;
            uint32_t recv = (uint32_t)__shfl_xor((int)send, 32);
            w_rt[rt] = recv | (hb ? lw1 : lw0);
        }
        uint32_t w0 = w_rt[0];
        uint32_t w1 = w_rt[1] & 0x0FFFFFFFu;
        *(uint2*)(h2b + (size_t)s * 128 + 2 * lane) = make_uint2(w0, w1);
    }
}

// ---------------------------------------------------------------------------
// lin2 v3 (R4, best measured): 32-sample blocks + register prefetch of next
// chunk's h2b words. grid = 1024.
// ---------------------------------------------------------------------------
__global__ __launch_bounds__(256) void lin2_kernel(
    const uint32_t* __restrict__ h2b,
    const uint4* __restrict__ wbfrag,
    const int* __restrict__ Tlin,
    uint32_t* __restrict__ h3w)
{
    __shared__ uint8_t As[32 * 520];     // 16,640 B

    int tid  = threadIdx.x;
    int lane = tid & 63;
    int wv   = __builtin_amdgcn_readfirstlane((int)(tid >> 6));
    int sblk = blockIdx.x >> 2;
    int jgrp = blockIdx.x & 3;
    int jt   = jgrp * 4 + wv;
    int s0   = sblk * 32;

    int T = Tlin[jt * 32 + (lane & 31)];
    int row  = lane & 31;
    int half = lane >> 5;

    int sm0 = tid >> 4,         wl0 = tid & 15;
    int sm1 = (256 + tid) >> 4, wl1 = tid & 15;
    const uint32_t* src0 = h2b + (size_t)(s0 + sm0) * 128 + wl0;
    const uint32_t* src1 = h2b + (size_t)(s0 + sm1) * 128 + wl1;

    v16i acc = {};
    uint32_t wreg0 = src0[0];
    uint32_t wreg1 = src1[0];

    for (int chunk = 0; chunk < 8; ++chunk) {
        {
            uint32_t dw[8];
            #pragma unroll
            for (int q = 0; q < 8; ++q)
                dw[q] = (((wreg0 >> (4 * q)) & 0xFu) * 0x204081u) & 0x01010101u;
            uint64_t* dst = (uint64_t*)(As + sm0 * 520 + wl0 * 32);
            dst[0] = (uint64_t)dw[0] | ((uint64_t)dw[1] << 32);
            dst[1] = (uint64_t)dw[2] | ((uint64_t)dw[3] << 32);
            dst[2] = (uint64_t)dw[4] | ((uint64_t)dw[5] << 32);
            dst[3] = (uint64_t)dw[6] | ((uint64_t)dw[7] << 32);
            #pragma unroll
            for (int q = 0; q < 8; ++q)
                dw[q] = (((wreg1 >> (4 * q)) & 0xFu) * 0x204081u) & 0x01010101u;
            dst = (uint64_t*)(As + sm1 * 520 + wl1 * 32);
            dst[0] = (uint64_t)dw[0] | ((uint64_t)dw[1] << 32);
            dst[1] = (uint64_t)dw[2] | ((uint64_t)dw[3] << 32);
            dst[2] = (uint64_t)dw[4] | ((uint64_t)dw[5] << 32);
            dst[3] = (uint64_t)dw[6] | ((uint64_t)dw[7] << 32);
        }
        __syncthreads();

        if (chunk < 7) {
            wreg0 = src0[(chunk + 1) * 16];
            wreg1 = src1[(chunk + 1) * 16];
        }

        const uint4* bsrc = wbfrag + ((size_t)jt * 128 + chunk * 16) * 64 + lane;
        #pragma unroll 4
        for (int kq = 0; kq < 16; ++kq) {
            uint4 bw = bsrc[kq * 64];
            v4i bf = {(int)bw.x, (int)bw.y, (int)bw.z, (int)bw.w};
            const uint8_t* ap = As + row * 520 + kq * 32 + half * 16;
            uint64_t lo0 = *(const uint64_t*)ap;
            uint64_t hi0 = *(const uint64_t*)(ap + 8);
            v4i a0 = {(int)(uint32_t)lo0, (int)(lo0 >> 32),
                      (int)(uint32_t)hi0, (int)(hi0 >> 32)};
            acc = __builtin_amdgcn_mfma_i32_32x32x32_i8(a0, bf, acc, 0, 0, 0);
        }
        __syncthreads();
    }

    #pragma unroll
    for (int r = 0; r < 16; ++r) {
        int row0 = (r & 3) + 8 * (r >> 2);
        uint64_t mk = __ballot(acc[r] >= T);
        if (lane == 0) {
            h3w[(size_t)(s0 + row0) * 16 + jt]     = (uint32_t)mk;
            h3w[(size_t)(s0 + row0 + 4) * 16 + jt] = (uint32_t)(mk >> 32);
        }
    }
}

// ---------------------------------------------------------------------------
// out kernel (R5 spread): 128 blocks x 64 threads
// ---------------------------------------------------------------------------
__global__ __launch_bounds__(64) void out_kernel(
    const uint32_t* __restrict__ h3w,
    const uint32_t* __restrict__ wout,
    const float* __restrict__ out_b,
    float* __restrict__ out)
{
    int s = blockIdx.x * 64 + threadIdx.x;
    const uint4* hp = (const uint4*)(h3w + (size_t)s * 16);
    uint4 q0 = hp[0], q1 = hp[1], q2 = hp[2], q3 = hp[3];
    uint32_t w[16] = {q0.x, q0.y, q0.z, q0.w, q1.x, q1.y, q1.z, q1.w,
                      q2.x, q2.y, q2.z, q2.w, q3.x, q3.y, q3.z, q3.w};
    int B = 0;
    #pragma unroll
    for (int k = 0; k < 16; ++k) B += __popc(w[k]);
    #pragma unroll
    for (int o = 0; o < 10; ++o) {
        int P = 0;
        #pragma unroll
        for (int k = 0; k < 16; ++k) P += __popc(w[k] & wout[o * 16 + k]);
        out[(size_t)s * 10 + o] = __fadd_rn((float)(2 * P - B), out_b[o]);
    }
}

// ---------------------------------------------------------------------------
extern "C" void kernel_launch(void* const* d_in, const int* in_sizes, int n_in,
                              void* d_out, int out_size, void* d_ws, size_t ws_size,
                              hipStream_t stream)
{
    const float* x       = (const float*)d_in[0];
    const float* conv1_w = (const float*)d_in[1];
    const float* conv1_b = (const float*)d_in[2];
    const float* bn1_g   = (const float*)d_in[3];
    const float* bn1_b   = (const float*)d_in[4];
    const float* bn1_m   = (const float*)d_in[5];
    const float* bn1_v   = (const float*)d_in[6];
    const float* conv2_w = (const float*)d_in[7];
    const float* conv2_b = (const float*)d_in[8];
    const float* bn2_g   = (const float*)d_in[9];
    const float* bn2_b   = (const float*)d_in[10];
    const float* bn2_m   = (const float*)d_in[11];
    const float* bn2_v   = (const float*)d_in[12];
    const float* lin_w   = (const float*)d_in[13];
    const float* lin_b   = (const float*)d_in[14];
    const float* out_w   = (const float*)d_in[15];
    const float* out_b   = (const float*)d_in[16];

    char* ws = (char*)d_ws;
    uint32_t* h2b    = (uint32_t*)(ws + 0);
    uint4*    wbfrag = (uint4*)   (ws + 4194304);
    uint32_t* h3w    = (uint32_t*)(ws + 6291456);
    uint32_t* cdat   = (uint32_t*)(ws + 6815744);
    uint32_t* lut    = (uint32_t*)(ws + 6818304);
    uint32_t* wout   = (uint32_t*)(ws + 6820352);
    int*      Tlin   = (int*)     (ws + 6820992);
    uint4*    wcfrag = (uint4*)   (ws + 6855808);

    pack_kernel<<<525, 256, 0, stream>>>(conv1_w, conv1_b, conv2_w, conv2_b,
                                         lin_w, lin_b, out_w,
                                         bn1_g, bn1_b, bn1_m, bn1_v,
                                         bn2_g, bn2_b, bn2_m, bn2_v,
                                         wbfrag, cdat, lut, wout, Tlin, wcfrag);
    conv_kernel<<<NB / 4, 256, 0, stream>>>(x, cdat, lut, wcfrag, h2b);
    lin2_kernel<<<1024, 256, 0, stream>>>(h2b, wbfrag, Tlin, h3w);
    out_kernel<<<128, 64, 0, stream>>>(h3w, wout, out_b, (float*)d_out);
}